// Round 1
// baseline (490.318 us; speedup 1.0000x reference)
//
#include <hip/hip_runtime.h>
#include <stdint.h>

#define NN   2048
#define DD   128
#define DIN  256
#define ROWZ 75

typedef float f32x4 __attribute__((ext_vector_type(4)));
typedef short bf16x8 __attribute__((ext_vector_type(8)));
typedef unsigned int u32x4 __attribute__((ext_vector_type(4)));
typedef unsigned int u32x2 __attribute__((ext_vector_type(2)));
typedef unsigned long long u64x2 __attribute__((ext_vector_type(2)));

__device__ __forceinline__ unsigned short f2bf(float x){
  union { float f; unsigned int u; } v; v.f = x;
  unsigned int u = v.u;
  u += 0x7fffu + ((u >> 16) & 1u);   // RNE
  return (unsigned short)(u >> 16);
}
__device__ __forceinline__ float bf2f(unsigned short b){
  union { float f; unsigned int u; } v; v.u = ((unsigned int)b) << 16;
  return v.f;
}

// ---------------------------------------------------------------------------
// Kernel A: Wh = h @ W (fp32), row L2 norms, PLUS fused adj bit-packing.
// R4: each wave packs one adj row per k-tile (32 coalesced dword loads issued
// right after the stage barrier, ballots after the FMA loop -> HBM latency
// hidden under ~1000cy of FMA). Output: adjp[row][64 u32], bit m&31 of word
// m>>5 = (adj_eye[row][m] > 0).
// ---------------------------------------------------------------------------
__launch_bounds__(256, 2)
__global__ void wh_kernel(const float* __restrict__ h, const float* __restrict__ W,
                          const int* __restrict__ adje,
                          unsigned short* __restrict__ whn, unsigned short* __restrict__ whT,
                          unsigned long long* __restrict__ adjp)
{
  __shared__ float hs[32][36];     // [k][row], pad 4: aligned + fewer bank conflicts
  __shared__ float Ws[32][128];
  __shared__ float ssp[32][33];
  __shared__ float sinv[32];

  const int t  = threadIdx.x;
  const int r0 = blockIdx.x * 32;        // global row base
  const int r4 = (t >> 5) * 4;           // row sub-base 0..28
  const int d4 = (t & 31) * 4;           // d sub-base 0..124

  const int wv = t >> 6;                 // wave id 0..3
  const int ln = t & 63;                 // lane

  float acc[4][4];
#pragma unroll
  for (int i = 0; i < 4; ++i)
#pragma unroll
    for (int j = 0; j < 4; ++j) acc[i][j] = 0.f;

  const int lrow = t >> 3;         // 0..31
  const int lkb  = (t & 7) * 4;    // 0,4,...,28

  for (int kt = 0; kt < 8; ++kt){
    __syncthreads();
    { // stage h tile transposed: hs[k][row]
      const float* src = h + (size_t)(r0 + lrow) * DIN + kt * 32 + lkb;
      f32x4 a = *(const f32x4*)src;
#pragma unroll
      for (int e = 0; e < 4; ++e) hs[lkb + e][lrow] = a[e];
    }
    { // stage W tile
      const int k = t >> 3;
      const int d = (t & 7) * 16;
      const float* src = W + (size_t)(kt * 32 + k) * DD + d;
      float* dst = &Ws[k][d];
#pragma unroll
      for (int e = 0; e < 4; ++e) ((f32x4*)dst)[e] = ((const f32x4*)src)[e];
    }
    __syncthreads();

    // ---- issue adj pack loads for this wave's row (row kt*4+wv of the block);
    //      32 coalesced wave-loads (8 KB/wave in flight) hidden under the FMAs
    const int grow = r0 + kt * 4 + wv;
    const int* arow = adje + (size_t)grow * NN;
    int pv[32];
#pragma unroll
    for (int j = 0; j < 32; ++j) pv[j] = arow[j * 64 + ln];

#pragma unroll
    for (int k = 0; k < 32; ++k){
      f32x4 w4 = *(const f32x4*)&Ws[k][d4];
      f32x4 ha = *(const f32x4*)&hs[k][r4];
#pragma unroll
      for (int i = 0; i < 4; ++i)
#pragma unroll
        for (int j = 0; j < 4; ++j)
          acc[i][j] += ha[i] * w4[j];
    }

    // ---- ballots + bitmask store (store traffic: 256 B/row, negligible)
#pragma unroll
    for (int j = 0; j < 32; j += 2){
      unsigned long long mA = __ballot(pv[j] > 0);
      unsigned long long mB = __ballot(pv[j + 1] > 0);
      if (ln == 0){
        u64x2 pk = { mA, mB };
        *(u64x2*)(adjp + (size_t)grow * 32 + j) = pk;
      }
    }
  }

  // row norms
#pragma unroll
  for (int i = 0; i < 4; ++i){
    float s = acc[i][0]*acc[i][0] + acc[i][1]*acc[i][1]
            + acc[i][2]*acc[i][2] + acc[i][3]*acc[i][3];
    ssp[r4 + i][t & 31] = s;
  }
  __syncthreads();
  if (t < 32){
    float ss = 0.f;
#pragma unroll
    for (int c = 0; c < 32; ++c) ss += ssp[t][c];
    sinv[t] = 1.0f / fmaxf(sqrtf(ss), 1e-12f);   // F.normalize eps semantics
  }
  __syncthreads();

  const int bb = r0 >> 11;
  const int n0 = (r0 & 2047) + r4;

  // whn: normalized bf16, row-major
#pragma unroll
  for (int i = 0; i < 4; ++i){
    const float inv = sinv[r4 + i];
    unsigned int lo = (unsigned int)f2bf(acc[i][0]*inv) | ((unsigned int)f2bf(acc[i][1]*inv) << 16);
    unsigned int hi = (unsigned int)f2bf(acc[i][2]*inv) | ((unsigned int)f2bf(acc[i][3]*inv) << 16);
    u32x2 pk = { lo, hi };
    *(u32x2*)(whn + (size_t)(r0 + r4 + i) * DD + d4) = pk;
  }
  // whT: unnormalized bf16, transposed [b][d][n] (8B store per d)
#pragma unroll
  for (int j = 0; j < 4; ++j){
    u32x2 pk;
#pragma unroll
    for (int e = 0; e < 2; ++e)
      pk[e] = (unsigned int)f2bf(acc[2*e][j]) | ((unsigned int)f2bf(acc[2*e + 1][j]) << 16);
    *(u32x2*)(whT + ((size_t)(bb * DD + d4 + j)) * NN + n0) = pk;
  }
}

// ---------------------------------------------------------------------------
// Kernel B: fused score -> mask/row-zero -> softmax(no-max) -> PV -> ELU.
// R4 changes vs R3:
//  - adj mask now read as BITS from LDS (8 KB staged once per block) instead
//    of 4 KB/wave/iter of global int32 -> attn's HBM traffic drops ~10x.
//  - batch = blockIdx&7: each batch's 1 MB K/V working set pins to one XCD L2.
//  - kf loads issued BEFORE Vt DMA so QK's vmcnt wait doesn't drain the DMA.
// ---------------------------------------------------------------------------
__launch_bounds__(256, 2)
__global__ void attn_kernel(const unsigned short* __restrict__ whn,
                            const unsigned short* __restrict__ whT,
                            const unsigned int* __restrict__ adjp,
                            float* __restrict__ out)
{
  __shared__ unsigned short Vt[128 * 128];      // 32 KB: V^T tile, swizzled granules
  __shared__ unsigned short Pbuf[4][32 * 40];   // 10 KB: per-wave P (stride 40 = 16B-aligned rows)
  __shared__ float linv_s[32];
  __shared__ unsigned int Ab[32 * 68];          // 8.5 KB adj bits, stride 68 breaks bank aliasing

  const int t    = threadIdx.x;
  const int w    = t >> 6;
  const int l    = t & 63;
  const int quad = l >> 4;
  const int l16  = l & 15;
  const int b     = blockIdx.x & 7;             // XCD-aligned batch
  const int qbase = (blockIdx.x >> 3) * 32;

  const unsigned short* whn_b = whn + (size_t)b * NN * DD;
  const unsigned short* whT_b = whT + (size_t)b * DD * NN;

  // ---- stage this block's 32 rows x 64 words of adj bits into LDS (8 KB) ----
  {
    const unsigned int* src = adjp + ((size_t)(b * NN + qbase + (t >> 3))) * 64 + (t & 7) * 8;
    u32x4 a0 = *(const u32x4*)src;
    u32x4 a1 = *(const u32x4*)(src + 4);
    unsigned int* dst = &Ab[(t >> 3) * 68 + (t & 7) * 8];
    *(u32x4*)dst = a0;
    *(u32x4*)(dst + 4) = a1;
  }

  // Q fragments (A-layout: row = lane&15, k = quad*8 + j), held all loop
  bf16x8 qf[2][4];
#pragma unroll
  for (int s = 0; s < 2; ++s)
#pragma unroll
    for (int kc = 0; kc < 4; ++kc)
      qf[s][kc] = *(const bf16x8*)(whn_b + (size_t)(qbase + s*16 + l16) * DD + kc*32 + quad*8);

  f32x4 oacc[2][8];
  float lacc[2][4];
#pragma unroll
  for (int s = 0; s < 2; ++s){
#pragma unroll
    for (int dt = 0; dt < 8; ++dt) oacc[s][dt] = (f32x4){0.f, 0.f, 0.f, 0.f};
#pragma unroll
    for (int r = 0; r < 4; ++r) lacc[s][r] = 0.f;
  }

  unsigned short* const Pw = &Pbuf[w][0];

  for (int it = 0; it < 16; ++it){
    const int m0 = it * 128;
    __syncthreads();   // prev iter's Vt reads done before DMA overwrite; Ab visible (it=0)

    // ---- kf fragments for both f, batched FIRST (QK then waits only on these) ----
    bf16x8 kf[2][4];
#pragma unroll
    for (int f = 0; f < 2; ++f)
#pragma unroll
      for (int kc = 0; kc < 4; ++kc)
        kf[f][kc] = *(const bf16x8*)(whn_b + (size_t)(m0 + w*32 + f*16 + l16) * DD + kc*32 + quad*8);

    // ---- stage V^T tile via async global->LDS (16B/lane, 4 d-rows/instr) ----
#pragma unroll
    for (int ii = 0; ii < 8; ++ii){
      const int d   = w*32 + ii*4 + quad;          // this lane's d row
      const int gsw = l16 ^ (d & 7);               // xor granule swizzle
      const unsigned short* src = whT_b + (size_t)d * NN + m0 + gsw * 8;
      __builtin_amdgcn_global_load_lds(
          (const __attribute__((address_space(1))) void*)src,
          (__attribute__((address_space(3))) void*)&Vt[(w*32 + ii*4) * 128],
          16, 0, 0);
    }

    // ---- adj mask words from LDS: word (it*4+w) of each q-row; bit = f*16+l16.
    //      16 lanes/quad hit the same address (broadcast); stride 68 -> 2-way max.
    unsigned int aw[2][4];
#pragma unroll
    for (int s = 0; s < 2; ++s)
#pragma unroll
      for (int r = 0; r < 4; ++r)
        aw[s][r] = Ab[(s*16 + quad*4 + r) * 68 + it*4 + w];

    // ---- QK + mask + exp -> P ----
#pragma unroll
    for (int f = 0; f < 2; ++f){
#pragma unroll
      for (int s = 0; s < 2; ++s){
        f32x4 sc = (f32x4){0.f, 0.f, 0.f, 0.f};
#pragma unroll
        for (int kc = 0; kc < 4; ++kc)
          sc = __builtin_amdgcn_mfma_f32_16x16x32_bf16(qf[s][kc], kf[f][kc], sc, 0, 0, 0);
#pragma unroll
        for (int r = 0; r < 4; ++r){
          const int qrow = qbase + s*16 + quad*4 + r;       // C row
          float sv = (qrow < ROWZ) ? 0.f : sc[r];           // row-zeroing bug emulation
          float p32 = ((aw[s][r] >> (f*16 + l16)) & 1u) ? __expf(sv) : 0.f;
          unsigned short pb = f2bf(p32);
          lacc[s][r] += bf2f(pb);
          Pw[(s*16 + quad*4 + r) * 40 + f*16 + l16] = pb;   // C-layout -> LDS
        }
      }
    }
    __syncthreads();   // drains vmcnt: Vt ready; P visible

    // ---- PV: out += P[16x32] * V[32x128] per q-subtile ----
#pragma unroll
    for (int s = 0; s < 2; ++s){
      bf16x8 pfr = *(const bf16x8*)&Pw[(s*16 + l16) * 40 + quad*8];  // A-layout read
#pragma unroll
      for (int dt = 0; dt < 8; ++dt){
        const int d  = dt*16 + l16;
        const int gg = (w*4 + quad) ^ (d & 7);
        bf16x8 vf = *(const bf16x8*)&Vt[d * 128 + gg * 8];
        oacc[s][dt] = __builtin_amdgcn_mfma_f32_16x16x32_bf16(pfr, vf, oacc[s][dt], 0, 0, 0);
      }
    }
  }

  // ---- l reduction (reuse own wave's Pbuf region as float scratch) ----
  {
    float* lredw = (float*)Pw;
#pragma unroll
    for (int s = 0; s < 2; ++s)
#pragma unroll
      for (int r = 0; r < 4; ++r)
        lredw[(s*16 + quad*4 + r) * 16 + l16] = lacc[s][r];
  }
  __syncthreads();
  if (t < 32){
    float sum = 0.f;
    for (int ww = 0; ww < 4; ++ww){
      const float* lr = (const float*)&Pbuf[ww][0];
#pragma unroll
      for (int c = 0; c < 16; ++c) sum += lr[t * 16 + c];
    }
    linv_s[t] = 1.0f / sum;
  }

  // ---- output reduction across waves (reuse Vt as 32KB float scratch) ----
  float* const ored = (float*)&Vt[0];
  for (int s = 0; s < 2; ++s){
    __syncthreads();   // linv visible / previous pass reads done
#pragma unroll
    for (int dt = 0; dt < 8; ++dt)
#pragma unroll
      for (int r = 0; r < 4; ++r)
        ored[w*2048 + (quad*4 + r)*128 + dt*16 + l16] = oacc[s][dt][r];
    __syncthreads();
#pragma unroll
    for (int j = 0; j < 8; ++j){
      const int o  = j*256 + t;
      const int ql = o >> 7, d = o & 127;
      float v = ored[ql*128 + d] + ored[2048 + ql*128 + d]
              + ored[4096 + ql*128 + d] + ored[6144 + ql*128 + d];
      v *= linv_s[s*16 + ql];
      v = (v > 0.f) ? v : expm1f(v);   // ELU (alpha=1)
      out[(size_t)(b*NN + qbase + s*16 + ql) * DD + d] = v;
    }
  }
}

extern "C" void kernel_launch(void* const* d_in, const int* in_sizes, int n_in,
                              void* d_out, int out_size, void* d_ws, size_t ws_size,
                              hipStream_t stream)
{
  const float* h       = (const float*)d_in[0];
  // d_in[1] = adj  (unused by the reference)
  const int*   adj_eye = (const int*)d_in[2];
  const float* W       = (const float*)d_in[3];
  float*       out     = (float*)d_out;

  unsigned short* whn  = (unsigned short*)d_ws;                   // 16384*128 bf16 = 4 MB
  unsigned short* whT  = whn + (size_t)16384 * 128;               // 8*128*2048 bf16 = 4 MB
  unsigned int*   adjp = (unsigned int*)(whT + (size_t)16384 * 128); // 16384*64 u32 = 4 MB

  wh_kernel<<<512, 256, 0, stream>>>(h, W, adj_eye, whn, whT, (unsigned long long*)adjp);
  attn_kernel<<<512, 256, 0, stream>>>(whn, whT, adjp, out);
}

// Round 2
// 321.965 us; speedup vs baseline: 1.5229x; 1.5229x over previous
//
#include <hip/hip_runtime.h>
#include <stdint.h>

#define NN   2048
#define DD   128
#define DIN  256
#define ROWZ 75

typedef float f32x4 __attribute__((ext_vector_type(4)));
typedef short bf16x8 __attribute__((ext_vector_type(8)));
typedef unsigned int u32x4 __attribute__((ext_vector_type(4)));
typedef unsigned int u32x2 __attribute__((ext_vector_type(2)));
typedef unsigned long long u64x2 __attribute__((ext_vector_type(2)));

__device__ __forceinline__ unsigned short f2bf(float x){
  union { float f; unsigned int u; } v; v.f = x;
  unsigned int u = v.u;
  u += 0x7fffu + ((u >> 16) & 1u);   // RNE
  return (unsigned short)(u >> 16);
}
__device__ __forceinline__ float bf2f(unsigned short b){
  union { float f; unsigned int u; } v; v.u = ((unsigned int)b) << 16;
  return v.f;
}

// ---------------------------------------------------------------------------
// Kernel P: adj bit-pack as a DEDICATED streaming kernel.
// R5: R4 fused this into wh_kernel -> pv[32] live across the FMA loop ->
// scratch spills (~134 MB each way, WRITE_SIZE 264 MB) -> 258 us. Here the
// working set is 8 VGPRs: chunk of 8 coalesced dword loads -> 8 ballots ->
// lane-0 stores. High occupancy + 8 loads in flight = streaming-BW-bound.
// Layout: bit (m&31) of u32 word (m>>5) = (adj_eye[row][m] > 0)  (LE u64).
// ---------------------------------------------------------------------------
__launch_bounds__(256, 8)
__global__ void pack_kernel(const int* __restrict__ adje,
                            unsigned long long* __restrict__ adjp)
{
  const int t  = threadIdx.x;
  const int wv = t >> 6;
  const int ln = t & 63;
  // 2048 blocks x 4 waves x 2 rows = 16384 rows
#pragma unroll
  for (int rr = 0; rr < 2; ++rr){
    const int row = blockIdx.x * 8 + wv * 2 + rr;
    const int* arow = adje + (size_t)row * NN;
    unsigned long long* drow = adjp + (size_t)row * 32;
#pragma unroll
    for (int c = 0; c < 4; ++c){
      int pv[8];
#pragma unroll
      for (int j = 0; j < 8; ++j) pv[j] = arow[c*512 + j*64 + ln];
      unsigned long long m[8];
#pragma unroll
      for (int j = 0; j < 8; ++j) m[j] = __ballot(pv[j] > 0);
      if (ln == 0){
#pragma unroll
        for (int j = 0; j < 8; j += 2){
          u64x2 pk = { m[j], m[j+1] };
          *(u64x2*)(drow + c*8 + j) = pk;
        }
      }
    }
  }
}

// ---------------------------------------------------------------------------
// Kernel A: Wh = h @ W (fp32), row L2 norms.  (R3 body, adj packing removed.)
// 512 blocks x 32 rows (2 blocks/CU, 2 waves/SIMD).
// hs padded to 36 floats/row: 16B-aligned rows + <=4-way store conflicts.
// ---------------------------------------------------------------------------
__launch_bounds__(256, 2)
__global__ void wh_kernel(const float* __restrict__ h, const float* __restrict__ W,
                          unsigned short* __restrict__ whn, unsigned short* __restrict__ whT)
{
  __shared__ float hs[32][36];     // [k][row], pad 4: aligned + fewer bank conflicts
  __shared__ float Ws[32][128];
  __shared__ float ssp[32][33];
  __shared__ float sinv[32];

  const int t  = threadIdx.x;
  const int r0 = blockIdx.x * 32;        // global row base
  const int r4 = (t >> 5) * 4;           // row sub-base 0..28
  const int d4 = (t & 31) * 4;           // d sub-base 0..124

  float acc[4][4];
#pragma unroll
  for (int i = 0; i < 4; ++i)
#pragma unroll
    for (int j = 0; j < 4; ++j) acc[i][j] = 0.f;

  const int lrow = t >> 3;         // 0..31
  const int lkb  = (t & 7) * 4;    // 0,4,...,28

  for (int kt = 0; kt < 8; ++kt){
    __syncthreads();
    { // stage h tile transposed: hs[k][row]
      const float* src = h + (size_t)(r0 + lrow) * DIN + kt * 32 + lkb;
      f32x4 a = *(const f32x4*)src;
#pragma unroll
      for (int e = 0; e < 4; ++e) hs[lkb + e][lrow] = a[e];
    }
    { // stage W tile
      const int k = t >> 3;
      const int d = (t & 7) * 16;
      const float* src = W + (size_t)(kt * 32 + k) * DD + d;
      float* dst = &Ws[k][d];
#pragma unroll
      for (int e = 0; e < 4; ++e) ((f32x4*)dst)[e] = ((const f32x4*)src)[e];
    }
    __syncthreads();
#pragma unroll
    for (int k = 0; k < 32; ++k){
      f32x4 w4 = *(const f32x4*)&Ws[k][d4];
      f32x4 ha = *(const f32x4*)&hs[k][r4];
#pragma unroll
      for (int i = 0; i < 4; ++i)
#pragma unroll
        for (int j = 0; j < 4; ++j)
          acc[i][j] += ha[i] * w4[j];
    }
  }

  // row norms
#pragma unroll
  for (int i = 0; i < 4; ++i){
    float s = acc[i][0]*acc[i][0] + acc[i][1]*acc[i][1]
            + acc[i][2]*acc[i][2] + acc[i][3]*acc[i][3];
    ssp[r4 + i][t & 31] = s;
  }
  __syncthreads();
  if (t < 32){
    float ss = 0.f;
#pragma unroll
    for (int c = 0; c < 32; ++c) ss += ssp[t][c];
    sinv[t] = 1.0f / fmaxf(sqrtf(ss), 1e-12f);   // F.normalize eps semantics
  }
  __syncthreads();

  const int bb = r0 >> 11;
  const int n0 = (r0 & 2047) + r4;

  // whn: normalized bf16, row-major
#pragma unroll
  for (int i = 0; i < 4; ++i){
    const float inv = sinv[r4 + i];
    unsigned int lo = (unsigned int)f2bf(acc[i][0]*inv) | ((unsigned int)f2bf(acc[i][1]*inv) << 16);
    unsigned int hi = (unsigned int)f2bf(acc[i][2]*inv) | ((unsigned int)f2bf(acc[i][3]*inv) << 16);
    u32x2 pk = { lo, hi };
    *(u32x2*)(whn + (size_t)(r0 + r4 + i) * DD + d4) = pk;
  }
  // whT: unnormalized bf16, transposed [b][d][n] (8B store per d)
#pragma unroll
  for (int j = 0; j < 4; ++j){
    u32x2 pk;
#pragma unroll
    for (int e = 0; e < 2; ++e)
      pk[e] = (unsigned int)f2bf(acc[2*e][j]) | ((unsigned int)f2bf(acc[2*e + 1][j]) << 16);
    *(u32x2*)(whT + ((size_t)(bb * DD + d4 + j)) * NN + n0) = pk;
  }
}

// ---------------------------------------------------------------------------
// Kernel B: fused score -> mask/row-zero -> softmax(no-max) -> PV -> ELU.
// (unchanged from R4 — verified passing)
//  - adj mask read as BITS from LDS (8 KB staged once per block).
//  - batch = blockIdx&7: each batch's 1 MB K/V working set pins to one XCD L2.
//  - kf loads issued BEFORE Vt DMA so QK's vmcnt wait doesn't drain the DMA.
// ---------------------------------------------------------------------------
__launch_bounds__(256, 2)
__global__ void attn_kernel(const unsigned short* __restrict__ whn,
                            const unsigned short* __restrict__ whT,
                            const unsigned int* __restrict__ adjp,
                            float* __restrict__ out)
{
  __shared__ unsigned short Vt[128 * 128];      // 32 KB: V^T tile, swizzled granules
  __shared__ unsigned short Pbuf[4][32 * 40];   // 10 KB: per-wave P (stride 40 = 16B-aligned rows)
  __shared__ float linv_s[32];
  __shared__ unsigned int Ab[32 * 68];          // 8.5 KB adj bits, stride 68 breaks bank aliasing

  const int t    = threadIdx.x;
  const int w    = t >> 6;
  const int l    = t & 63;
  const int quad = l >> 4;
  const int l16  = l & 15;
  const int b     = blockIdx.x & 7;             // XCD-aligned batch
  const int qbase = (blockIdx.x >> 3) * 32;

  const unsigned short* whn_b = whn + (size_t)b * NN * DD;
  const unsigned short* whT_b = whT + (size_t)b * DD * NN;

  // ---- stage this block's 32 rows x 64 words of adj bits into LDS (8 KB) ----
  {
    const unsigned int* src = adjp + ((size_t)(b * NN + qbase + (t >> 3))) * 64 + (t & 7) * 8;
    u32x4 a0 = *(const u32x4*)src;
    u32x4 a1 = *(const u32x4*)(src + 4);
    unsigned int* dst = &Ab[(t >> 3) * 68 + (t & 7) * 8];
    *(u32x4*)dst = a0;
    *(u32x4*)(dst + 4) = a1;
  }

  // Q fragments (A-layout: row = lane&15, k = quad*8 + j), held all loop
  bf16x8 qf[2][4];
#pragma unroll
  for (int s = 0; s < 2; ++s)
#pragma unroll
    for (int kc = 0; kc < 4; ++kc)
      qf[s][kc] = *(const bf16x8*)(whn_b + (size_t)(qbase + s*16 + l16) * DD + kc*32 + quad*8);

  f32x4 oacc[2][8];
  float lacc[2][4];
#pragma unroll
  for (int s = 0; s < 2; ++s){
#pragma unroll
    for (int dt = 0; dt < 8; ++dt) oacc[s][dt] = (f32x4){0.f, 0.f, 0.f, 0.f};
#pragma unroll
    for (int r = 0; r < 4; ++r) lacc[s][r] = 0.f;
  }

  unsigned short* const Pw = &Pbuf[w][0];

  for (int it = 0; it < 16; ++it){
    const int m0 = it * 128;
    __syncthreads();   // prev iter's Vt reads done before DMA overwrite; Ab visible (it=0)

    // ---- kf fragments for both f, batched FIRST (QK then waits only on these) ----
    bf16x8 kf[2][4];
#pragma unroll
    for (int f = 0; f < 2; ++f)
#pragma unroll
      for (int kc = 0; kc < 4; ++kc)
        kf[f][kc] = *(const bf16x8*)(whn_b + (size_t)(m0 + w*32 + f*16 + l16) * DD + kc*32 + quad*8);

    // ---- stage V^T tile via async global->LDS (16B/lane, 4 d-rows/instr) ----
#pragma unroll
    for (int ii = 0; ii < 8; ++ii){
      const int d   = w*32 + ii*4 + quad;          // this lane's d row
      const int gsw = l16 ^ (d & 7);               // xor granule swizzle
      const unsigned short* src = whT_b + (size_t)d * NN + m0 + gsw * 8;
      __builtin_amdgcn_global_load_lds(
          (const __attribute__((address_space(1))) void*)src,
          (__attribute__((address_space(3))) void*)&Vt[(w*32 + ii*4) * 128],
          16, 0, 0);
    }

    // ---- adj mask words from LDS: word (it*4+w) of each q-row; bit = f*16+l16.
    //      16 lanes/quad hit the same address (broadcast); stride 68 -> 2-way max.
    unsigned int aw[2][4];
#pragma unroll
    for (int s = 0; s < 2; ++s)
#pragma unroll
      for (int r = 0; r < 4; ++r)
        aw[s][r] = Ab[(s*16 + quad*4 + r) * 68 + it*4 + w];

    // ---- QK + mask + exp -> P ----
#pragma unroll
    for (int f = 0; f < 2; ++f){
#pragma unroll
      for (int s = 0; s < 2; ++s){
        f32x4 sc = (f32x4){0.f, 0.f, 0.f, 0.f};
#pragma unroll
        for (int kc = 0; kc < 4; ++kc)
          sc = __builtin_amdgcn_mfma_f32_16x16x32_bf16(qf[s][kc], kf[f][kc], sc, 0, 0, 0);
#pragma unroll
        for (int r = 0; r < 4; ++r){
          const int qrow = qbase + s*16 + quad*4 + r;       // C row
          float sv = (qrow < ROWZ) ? 0.f : sc[r];           // row-zeroing bug emulation
          float p32 = ((aw[s][r] >> (f*16 + l16)) & 1u) ? __expf(sv) : 0.f;
          unsigned short pb = f2bf(p32);
          lacc[s][r] += bf2f(pb);
          Pw[(s*16 + quad*4 + r) * 40 + f*16 + l16] = pb;   // C-layout -> LDS
        }
      }
    }
    __syncthreads();   // drains vmcnt: Vt ready; P visible

    // ---- PV: out += P[16x32] * V[32x128] per q-subtile ----
#pragma unroll
    for (int s = 0; s < 2; ++s){
      bf16x8 pfr = *(const bf16x8*)&Pw[(s*16 + l16) * 40 + quad*8];  // A-layout read
#pragma unroll
      for (int dt = 0; dt < 8; ++dt){
        const int d  = dt*16 + l16;
        const int gg = (w*4 + quad) ^ (d & 7);
        bf16x8 vf = *(const bf16x8*)&Vt[d * 128 + gg * 8];
        oacc[s][dt] = __builtin_amdgcn_mfma_f32_16x16x32_bf16(pfr, vf, oacc[s][dt], 0, 0, 0);
      }
    }
  }

  // ---- l reduction (reuse own wave's Pbuf region as float scratch) ----
  {
    float* lredw = (float*)Pw;
#pragma unroll
    for (int s = 0; s < 2; ++s)
#pragma unroll
      for (int r = 0; r < 4; ++r)
        lredw[(s*16 + quad*4 + r) * 16 + l16] = lacc[s][r];
  }
  __syncthreads();
  if (t < 32){
    float sum = 0.f;
    for (int ww = 0; ww < 4; ++ww){
      const float* lr = (const float*)&Pbuf[ww][0];
#pragma unroll
      for (int c = 0; c < 16; ++c) sum += lr[t * 16 + c];
    }
    linv_s[t] = 1.0f / sum;
  }

  // ---- output reduction across waves (reuse Vt as 32KB float scratch) ----
  float* const ored = (float*)&Vt[0];
  for (int s = 0; s < 2; ++s){
    __syncthreads();   // linv visible / previous pass reads done
#pragma unroll
    for (int dt = 0; dt < 8; ++dt)
#pragma unroll
      for (int r = 0; r < 4; ++r)
        ored[w*2048 + (quad*4 + r)*128 + dt*16 + l16] = oacc[s][dt][r];
    __syncthreads();
#pragma unroll
    for (int j = 0; j < 8; ++j){
      const int o  = j*256 + t;
      const int ql = o >> 7, d = o & 127;
      float v = ored[ql*128 + d] + ored[2048 + ql*128 + d]
              + ored[4096 + ql*128 + d] + ored[6144 + ql*128 + d];
      v *= linv_s[s*16 + ql];
      v = (v > 0.f) ? v : expm1f(v);   // ELU (alpha=1)
      out[(size_t)(b*NN + qbase + s*16 + ql) * DD + d] = v;
    }
  }
}

extern "C" void kernel_launch(void* const* d_in, const int* in_sizes, int n_in,
                              void* d_out, int out_size, void* d_ws, size_t ws_size,
                              hipStream_t stream)
{
  const float* h       = (const float*)d_in[0];
  // d_in[1] = adj  (unused by the reference)
  const int*   adj_eye = (const int*)d_in[2];
  const float* W       = (const float*)d_in[3];
  float*       out     = (float*)d_out;

  unsigned short* whn  = (unsigned short*)d_ws;                   // 16384*128 bf16 = 4 MB
  unsigned short* whT  = whn + (size_t)16384 * 128;               // 8*128*2048 bf16 = 4 MB
  unsigned int*   adjp = (unsigned int*)(whT + (size_t)16384 * 128); // 16384*64 u32 = 4 MB

  pack_kernel<<<2048, 256, 0, stream>>>(adj_eye, (unsigned long long*)adjp);
  wh_kernel<<<512, 256, 0, stream>>>(h, W, whn, whT);
  attn_kernel<<<512, 256, 0, stream>>>(whn, whT, adjp, out);
}